// Round 4
// baseline (426.705 us; speedup 1.0000x reference)
//
#include <hip/hip_runtime.h>
#include <stdint.h>

typedef unsigned short ushort_t;
typedef __attribute__((ext_vector_type(8)))  __bf16 bf16x8;
typedef __attribute__((ext_vector_type(16))) float  f32x16;

// ---------- helpers ----------

__device__ __forceinline__ unsigned int f2bf(float f) {
    unsigned int u = __float_as_uint(f);
    return (u + 0x7FFFu + ((u >> 16) & 1u)) >> 16;  // RNE
}

// Cayley sign for e_a * e_b in Cl(4,1), SIG = [1,1,1,1,-1]
__device__ __forceinline__ float cayley_sign(int a, int b) {
    int s = 0;
    int aa = a >> 1;
    while (aa) { s += __popc(aa & b); aa >>= 1; }
    float sign = (s & 1) ? -1.0f : 1.0f;
    if (a & b & 16) sign = -sign;   // only SIG[4] = -1
    return sign;
}

// async global->LDS, 16 bytes per lane. LDS dest is wave-uniform base + lane*16.
__device__ __forceinline__ void async16(const ushort_t* g, const ushort_t* l) {
    const __attribute__((address_space(1))) unsigned int* gp =
        (const __attribute__((address_space(1))) unsigned int*)(uintptr_t)g;
    __attribute__((address_space(3))) unsigned int* lp =
        (__attribute__((address_space(3))) unsigned int*)(unsigned int)(uintptr_t)l;
    __builtin_amdgcn_global_load_lds(gp, lp, 16, 0, 0);
}

// ---------- B prep (Cayley-folded weight), fat-block grid-stride ----------
// Chunk(n_blk, k_blk) = 4096 bf16: [kq(4)][col(128)][j(8)].
// 1024 blocks x 256 threads, 8 virtual blocks each.
__global__ __launch_bounds__(256) void prepB(const float* __restrict__ w,
                                             ushort_t* __restrict__ B_sw) {
    const int t = threadIdx.x;               // 0..255
    const int kq = t & 3;                    // 0..3
#pragma unroll
    for (int i = 0; i < 8; ++i) {
        const int vb = blockIdx.x + i * 1024;    // 0..8191 = 128 k_blk x 64 y
        const int k_blk = vb & 127;
        const int y     = vb >> 7;               // 0..63
        const int p_blk = y >> 1;                // 0..31
        const int r     = (y & 1) * 64 + (t >> 2);   // 0..127
        const int n  = p_blk * 128 + r;
        const int o  = n >> 5;
        const int kc = n & 31;
        const float* wrow = w + (size_t)o * 4096 + (size_t)k_blk * 32;
        unsigned int pk[4];
#pragma unroll
        for (int pr = 0; pr < 4; ++pr) {
            const int i0 = kq * 8 + pr * 2, i1 = i0 + 1;
            const int j0 = i0 ^ kc, j1 = i1 ^ kc;
            float v0 = wrow[j0] * cayley_sign(i0, j0);
            float v1 = wrow[j1] * cayley_sign(i1, j1);
            pk[pr] = f2bf(v0) | (f2bf(v1) << 16);
        }
        uint4 u = {pk[0], pk[1], pk[2], pk[3]};
        ushort_t* chunk = B_sw + ((size_t)p_blk * 128 + k_blk) * 4096;
        *(uint4*)(chunk + kq * 1024 + r * 8) = u;
    }
}

// ---------- GEMM (32x32x16 bf16 MFMA) + fused A-conversion + fused norm ----------
// A is staged straight from x (f32): global_load -> cvt/pack bf16 -> ds_write,
// issued around the MFMA block so load latency overlaps compute. B is staged
// via global_load_lds (async). Single barrier per K-iter, double-buffered LDS.
__global__ __launch_bounds__(256) void gemm_norm(const float* __restrict__ x,
                                                 const ushort_t* __restrict__ B_sw,
                                                 float* __restrict__ out) {
    __shared__ ushort_t As[2][4096];  // 2 x 8 KiB  [kq][row][j]
    __shared__ ushort_t Bs[2][4096];  // 2 x 8 KiB  [kq][col][j]

    const int n_blk = blockIdx.x;  // 0..31
    const int m_blk = blockIdx.y;  // 0..31
    const int t = threadIdx.x;
    const int wave = t >> 6;
    const int lane = t & 63;
    const int half = lane >> 5;    // k-subgroup for 32x32x16
    const int l32  = lane & 31;
    const int wr = wave >> 1;      // wave row (0..1)
    const int wc = wave & 1;       // wave col (0..1)

    // A-staging role: thread owns (row ar, 16 consecutive k at kh2*16)
    const int ar  = t >> 1;        // 0..127
    const int kh2 = t & 1;         // 0..1

    f32x16 acc[2][2];
#pragma unroll
    for (int a = 0; a < 2; ++a)
#pragma unroll
        for (int b = 0; b < 2; ++b)
#pragma unroll
            for (int i = 0; i < 16; ++i) acc[a][b][i] = 0.0f;

    const float* xRow = x + (size_t)(m_blk * 128 + ar) * 4096 + kh2 * 16;
    const ushort_t* bPanel = B_sw + (size_t)n_blk * 128 * 4096;

    // prologue: stage k-chunk 0
    async16(bPanel + t * 8,        Bs[0] + wave * 512);
    async16(bPanel + 2048 + t * 8, Bs[0] + 2048 + wave * 512);
    {
        const float4* src = (const float4*)(xRow);
        float4 f0 = src[0], f1 = src[1], f2 = src[2], f3 = src[3];
        uint4 p0, p1;
        p0.x = f2bf(f0.x) | (f2bf(f0.y) << 16);
        p0.y = f2bf(f0.z) | (f2bf(f0.w) << 16);
        p0.z = f2bf(f1.x) | (f2bf(f1.y) << 16);
        p0.w = f2bf(f1.z) | (f2bf(f1.w) << 16);
        p1.x = f2bf(f2.x) | (f2bf(f2.y) << 16);
        p1.y = f2bf(f2.z) | (f2bf(f2.w) << 16);
        p1.z = f2bf(f3.x) | (f2bf(f3.y) << 16);
        p1.w = f2bf(f3.z) | (f2bf(f3.w) << 16);
        *(uint4*)&As[0][(2 * kh2) * 1024 + ar * 8]     = p0;  // kq = 2*kh2
        *(uint4*)&As[0][(2 * kh2 + 1) * 1024 + ar * 8] = p1;  // kq = 2*kh2+1
    }

    for (int kb = 0; kb < 128; ++kb) {
        const int cur = kb & 1;
        const int nxt = cur ^ 1;
        __syncthreads();   // buf[cur] staged; buf[nxt] safe to overwrite

        // issue next chunk's loads first so they fly during the MFMA block
        float4 f0, f1, f2, f3;
        if (kb + 1 < 128) {
            const ushort_t* gB = bPanel + (size_t)(kb + 1) * 4096;
            async16(gB + t * 8,        Bs[nxt] + wave * 512);
            async16(gB + 2048 + t * 8, Bs[nxt] + 2048 + wave * 512);
            const float4* src = (const float4*)(xRow + (size_t)(kb + 1) * 32);
            f0 = src[0]; f1 = src[1]; f2 = src[2]; f3 = src[3];
        }

        // fragments: A[m=l32][k = kh*16 + half*8 + j]
        bf16x8 aF[2][2], bF[2][2];   // [tile][kh]
#pragma unroll
        for (int tm = 0; tm < 2; ++tm)
#pragma unroll
            for (int kh = 0; kh < 2; ++kh)
                aF[tm][kh] = *(const bf16x8*)&As[cur][(kh * 2 + half) * 1024 + (wr * 64 + tm * 32 + l32) * 8];
#pragma unroll
        for (int tn = 0; tn < 2; ++tn)
#pragma unroll
            for (int kh = 0; kh < 2; ++kh)
                bF[tn][kh] = *(const bf16x8*)&Bs[cur][(kh * 2 + half) * 1024 + (wc * 64 + tn * 32 + l32) * 8];

#pragma unroll
        for (int tm = 0; tm < 2; ++tm)
#pragma unroll
            for (int tn = 0; tn < 2; ++tn) {
                acc[tm][tn] = __builtin_amdgcn_mfma_f32_32x32x16_bf16(aF[tm][0], bF[tn][0], acc[tm][tn], 0, 0, 0);
                acc[tm][tn] = __builtin_amdgcn_mfma_f32_32x32x16_bf16(aF[tm][1], bF[tn][1], acc[tm][tn], 0, 0, 0);
            }

        // convert + write next A chunk into LDS (before next barrier)
        if (kb + 1 < 128) {
            uint4 p0, p1;
            p0.x = f2bf(f0.x) | (f2bf(f0.y) << 16);
            p0.y = f2bf(f0.z) | (f2bf(f0.w) << 16);
            p0.z = f2bf(f1.x) | (f2bf(f1.y) << 16);
            p0.w = f2bf(f1.z) | (f2bf(f1.w) << 16);
            p1.x = f2bf(f2.x) | (f2bf(f2.y) << 16);
            p1.y = f2bf(f2.z) | (f2bf(f2.w) << 16);
            p1.z = f2bf(f3.x) | (f2bf(f3.y) << 16);
            p1.w = f2bf(f3.z) | (f2bf(f3.w) << 16);
            *(uint4*)&As[nxt][(2 * kh2) * 1024 + ar * 8]     = p0;
            *(uint4*)&As[nxt][(2 * kh2 + 1) * 1024 + ar * 8] = p1;
        }
    }

    // Epilogue: fused normalization. 32x32 C/D layout (m74/m101):
    // col = lane&31, row = (reg&3) + 8*(reg>>2) + 4*(lane>>5).
    const int row0 = m_blk * 128 + wr * 64;
    const int col0 = n_blk * 128 + wc * 64;
#pragma unroll
    for (int tm = 0; tm < 2; ++tm) {
#pragma unroll
        for (int tn = 0; tn < 2; ++tn) {
            const int cbase = col0 + tn * 32 + l32;
#pragma unroll
            for (int reg = 0; reg < 16; ++reg) {
                float v = acc[tm][tn][reg];
                float p = v * v;
                p += __shfl_xor(p, 1);
                p += __shfl_xor(p, 2);
                p += __shfl_xor(p, 4);
                p += __shfl_xor(p, 8);
                p += __shfl_xor(p, 16);   // stays within the 32-lane half
                const float inv = rsqrtf(p + 1e-6f);
                const int row = row0 + tm * 32 + (reg & 3) + 8 * (reg >> 2) + 4 * half;
                out[(size_t)row * 4096 + cbase] = v * inv;
            }
        }
    }
}

// ---------- launch ----------

extern "C" void kernel_launch(void* const* d_in, const int* in_sizes, int n_in,
                              void* d_out, int out_size, void* d_ws, size_t ws_size,
                              hipStream_t stream) {
    const float* x = (const float*)d_in[0];     // 4096 x 128 x 32 f32
    const float* w = (const float*)d_in[1];     // 128 x 128 x 32 f32
    float* out = (float*)d_out;                 // 4096 x 128 x 32 f32

    ushort_t* B_sw = (ushort_t*)d_ws;           // 32 MiB

    prepB<<<dim3(1024), 256, 0, stream>>>(w, B_sw);
    gemm_norm<<<dim3(32, 32), 256, 0, stream>>>(x, B_sw, out);
}

// Round 5
// 352.293 us; speedup vs baseline: 1.2112x; 1.2112x over previous
//
#include <hip/hip_runtime.h>
#include <stdint.h>

typedef unsigned short ushort_t;
typedef __attribute__((ext_vector_type(8)))  __bf16 bf16x8;
typedef __attribute__((ext_vector_type(16))) float  f32x16;

// ---------- helpers ----------

__device__ __forceinline__ unsigned int f2bf(float f) {
    unsigned int u = __float_as_uint(f);
    return (u + 0x7FFFu + ((u >> 16) & 1u)) >> 16;  // RNE
}

// Cayley sign for e_a * e_b in Cl(4,1), SIG = [1,1,1,1,-1]
__device__ __forceinline__ float cayley_sign(int a, int b) {
    int s = 0;
    int aa = a >> 1;
    while (aa) { s += __popc(aa & b); aa >>= 1; }
    float sign = (s & 1) ? -1.0f : 1.0f;
    if (a & b & 16) sign = -sign;   // only SIG[4] = -1
    return sign;
}

// async global->LDS, 16 bytes per lane. LDS dest is wave-uniform base + lane*16.
__device__ __forceinline__ void async16(const ushort_t* g, const ushort_t* l) {
    const __attribute__((address_space(1))) unsigned int* gp =
        (const __attribute__((address_space(1))) unsigned int*)(uintptr_t)g;
    __attribute__((address_space(3))) unsigned int* lp =
        (__attribute__((address_space(3))) unsigned int*)(unsigned int)(uintptr_t)l;
    __builtin_amdgcn_global_load_lds(gp, lp, 16, 0, 0);
}

// ---------- merged prep kernel (R3, known-good) ----------
// Swizzled operand chunk(blk, k_blk) = 4096 bf16: [kq(4)][row(128)][j(8)],
// element offset = kq*1024 + row*8 + j, k = kq*8 + j.
__global__ __launch_bounds__(256) void prepAB(const float* __restrict__ x,
                                              const float* __restrict__ w,
                                              ushort_t* __restrict__ A_sw,
                                              ushort_t* __restrict__ B_sw) {
    const int k_blk = blockIdx.x;            // 0..127
    const int p_blk = blockIdx.y >> 1;       // 0..31
    const int sub   = blockIdx.y & 1;        // 0..1
    const int t = threadIdx.x;               // 0..255
    const int r  = sub * 64 + (t >> 2);      // 0..127
    const int kq = t & 3;                    // 0..3

    if (blockIdx.z == 0) {
        const float* src = x + (size_t)(p_blk * 128 + r) * 4096 + (size_t)k_blk * 32 + kq * 8;
        float4 a = ((const float4*)src)[0];
        float4 b = ((const float4*)src)[1];
        uint4 pk;
        pk.x = f2bf(a.x) | (f2bf(a.y) << 16);
        pk.y = f2bf(a.z) | (f2bf(a.w) << 16);
        pk.z = f2bf(b.x) | (f2bf(b.y) << 16);
        pk.w = f2bf(b.z) | (f2bf(b.w) << 16);
        ushort_t* chunk = A_sw + ((size_t)p_blk * 128 + k_blk) * 4096;
        *(uint4*)(chunk + kq * 1024 + r * 8) = pk;
    } else {
        const int n = p_blk * 128 + r;
        const int o = n >> 5;
        const int kc = n & 31;
        const float* wrow = w + (size_t)o * 4096 + (size_t)k_blk * 32;
        unsigned int pk[4];
#pragma unroll
        for (int pr = 0; pr < 4; ++pr) {
            const int i0 = kq * 8 + pr * 2, i1 = i0 + 1;
            const int j0 = i0 ^ kc, j1 = i1 ^ kc;
            float v0 = wrow[j0] * cayley_sign(i0, j0);
            float v1 = wrow[j1] * cayley_sign(i1, j1);
            pk[pr] = f2bf(v0) | (f2bf(v1) << 16);
        }
        uint4 u = {pk[0], pk[1], pk[2], pk[3]};
        ushort_t* chunk = B_sw + ((size_t)p_blk * 128 + k_blk) * 4096;
        *(uint4*)(chunk + kq * 1024 + r * 8) = u;
    }
}

// ---------- GEMM: BK=64, A in registers from global, B dbuf LDS ----------
__global__ __launch_bounds__(256) void gemm_norm(const ushort_t* __restrict__ A_sw,
                                                 const ushort_t* __restrict__ B_sw,
                                                 float* __restrict__ out) {
    __shared__ ushort_t Bs[2][8192];  // 2 x 16 KiB: [c(2)][kq(4)][col(128)][j(8)]

    // 4x8 supertile swizzle: 32 consecutive blocks share 4 m-panels x 8 n-panels
    const int bid = blockIdx.x;                    // 0..1023
    const int sup = bid >> 5;                      // 0..31
    const int m_blk = (sup >> 2) * 4 + ((bid >> 3) & 3);   // 0..31
    const int n_blk = (sup & 3) * 8 + (bid & 7);           // 0..31

    const int t = threadIdx.x;
    const int wave = t >> 6;
    const int lane = t & 63;
    const int half = lane >> 5;    // k-subgroup for 32x32x16
    const int l32  = lane & 31;
    const int wr = wave >> 1;      // wave row (0..1)
    const int wc = wave & 1;       // wave col (0..1)

    f32x16 acc[2][2];
#pragma unroll
    for (int a = 0; a < 2; ++a)
#pragma unroll
        for (int b = 0; b < 2; ++b)
#pragma unroll
            for (int i = 0; i < 16; ++i) acc[a][b][i] = 0.0f;

    const ushort_t* aPanel = A_sw + (size_t)m_blk * 128 * 4096;
    const ushort_t* bPanel = B_sw + (size_t)n_blk * 128 * 4096;

    // per-thread A fragment base offsets (elements): chunk c, kq plane, row
    const int rA0 = wr * 64 + 0  + l32;   // tm = 0
    const int rA1 = wr * 64 + 32 + l32;   // tm = 1
    const int cB  = wc * 64 + l32;        // B col base within panel (tn via +32)

    // prologue: stage B chunk-pair 0 into buffer 0 (16 KiB, 4 linear async16)
#pragma unroll
    for (int i = 0; i < 4; ++i)
        async16(bPanel + i * 2048 + t * 8, Bs[0] + i * 2048 + t * 8);

    for (int kb = 0; kb < 64; ++kb) {
        const int cur = kb & 1;
        __syncthreads();   // B buf[cur] staged; buf[cur^1] safe to overwrite

        // prefetch next B chunk-pair (lands during this iter's compute)
        if (kb + 1 < 64) {
            const ushort_t* gB = bPanel + (size_t)(kb + 1) * 8192;
#pragma unroll
            for (int i = 0; i < 4; ++i)
                async16(gB + i * 2048 + t * 8, Bs[cur ^ 1] + i * 2048 + t * 8);
        }

        // A fragments straight from global (L2-resident panel), lane-consecutive 16B
        const ushort_t* gA = aPanel + (size_t)kb * 8192;
        bf16x8 aF[2][4], bF[2][4];   // [tile][ks]
#pragma unroll
        for (int ks = 0; ks < 4; ++ks) {
            const int el = (ks >> 1) * 4096 + ((ks & 1) * 2 + half) * 1024;
            aF[0][ks] = *(const bf16x8*)(gA + el + rA0 * 8);
            aF[1][ks] = *(const bf16x8*)(gA + el + rA1 * 8);
        }
#pragma unroll
        for (int ks = 0; ks < 4; ++ks) {
            const int el = (ks >> 1) * 4096 + ((ks & 1) * 2 + half) * 1024;
            bF[0][ks] = *(const bf16x8*)&Bs[cur][el + cB * 8];
            bF[1][ks] = *(const bf16x8*)&Bs[cur][el + (cB + 32) * 8];
        }

#pragma unroll
        for (int ks = 0; ks < 4; ++ks) {
            acc[0][0] = __builtin_amdgcn_mfma_f32_32x32x16_bf16(aF[0][ks], bF[0][ks], acc[0][0], 0, 0, 0);
            acc[0][1] = __builtin_amdgcn_mfma_f32_32x32x16_bf16(aF[0][ks], bF[1][ks], acc[0][1], 0, 0, 0);
            acc[1][0] = __builtin_amdgcn_mfma_f32_32x32x16_bf16(aF[1][ks], bF[0][ks], acc[1][0], 0, 0, 0);
            acc[1][1] = __builtin_amdgcn_mfma_f32_32x32x16_bf16(aF[1][ks], bF[1][ks], acc[1][1], 0, 0, 0);
        }
    }

    // Epilogue: fused normalization. 32x32 C/D layout:
    // col = lane&31, row = (reg&3) + 8*(reg>>2) + 4*(lane>>5).
    const int row0 = m_blk * 128 + wr * 64;
    const int col0 = n_blk * 128 + wc * 64;
#pragma unroll
    for (int tm = 0; tm < 2; ++tm) {
#pragma unroll
        for (int tn = 0; tn < 2; ++tn) {
            const int cbase = col0 + tn * 32 + l32;
#pragma unroll
            for (int reg = 0; reg < 16; ++reg) {
                float v = acc[tm][tn][reg];
                float p = v * v;
                p += __shfl_xor(p, 1);
                p += __shfl_xor(p, 2);
                p += __shfl_xor(p, 4);
                p += __shfl_xor(p, 8);
                p += __shfl_xor(p, 16);   // stays within the 32-lane half
                const float inv = rsqrtf(p + 1e-6f);
                const int row = row0 + tm * 32 + (reg & 3) + 8 * (reg >> 2) + 4 * half;
                out[(size_t)row * 4096 + cbase] = v * inv;
            }
        }
    }
}

// ---------- launch ----------

extern "C" void kernel_launch(void* const* d_in, const int* in_sizes, int n_in,
                              void* d_out, int out_size, void* d_ws, size_t ws_size,
                              hipStream_t stream) {
    const float* x = (const float*)d_in[0];     // 4096 x 128 x 32 f32
    const float* w = (const float*)d_in[1];     // 128 x 128 x 32 f32
    float* out = (float*)d_out;                 // 4096 x 128 x 32 f32

    ushort_t* A_sw = (ushort_t*)d_ws;                       // 32 MiB
    ushort_t* B_sw = A_sw + (size_t)4096 * 4096;            // 32 MiB

    prepAB<<<dim3(128, 64, 2), 256, 0, stream>>>(x, w, A_sw, B_sw);
    gemm_norm<<<dim3(1024), 256, 0, stream>>>(A_sw, B_sw, out);
}